// Round 1
// baseline (1608.497 us; speedup 1.0000x reference)
//
#include <hip/hip_runtime.h>
#include <cstdint>
#include <cstddef>

#define N_B 4
#define D_F 512
#define L_S 2048
#define H_N 8
#define DH  64
#define C3  (3*D_F)   // 1536

// ---------------------------------------------------------------------------
// GEMM: Y[n][o][l] = sum_c W[o][c] * X[n][c][l]
// grid: (L/256, O/64, N), block 256 threads. Each thread owns one l, 64 o's.
// ---------------------------------------------------------------------------
__global__ __launch_bounds__(256) void gemm_ncl(const float* __restrict__ W,
                                                const float* __restrict__ X,
                                                float* __restrict__ Y,
                                                int O, int C) {
    __shared__ float w_s[64 * 8];
    const int tid = threadIdx.x;
    const int l   = blockIdx.x * 256 + tid;
    const int o0  = blockIdx.y * 64;
    const int n   = blockIdx.z;
    const float* Xn = X + (size_t)n * C * L_S;

    float acc[64];
#pragma unroll
    for (int i = 0; i < 64; ++i) acc[i] = 0.f;

    for (int c0 = 0; c0 < C; c0 += 8) {
        __syncthreads();
#pragma unroll
        for (int r = 0; r < 2; ++r) {
            int ff = tid + r * 256;          // 512 elements: 64 o x 8 c
            int oo = ff >> 3, cc = ff & 7;
            w_s[ff] = W[(size_t)(o0 + oo) * C + c0 + cc];
        }
        __syncthreads();

        float xr[8];
#pragma unroll
        for (int j = 0; j < 8; ++j) xr[j] = Xn[(size_t)(c0 + j) * L_S + l];

#pragma unroll
        for (int o = 0; o < 64; ++o) {
            const float4* wp = (const float4*)(&w_s[o * 8]);
            float4 a = wp[0], b = wp[1];
            acc[o] += a.x * xr[0] + a.y * xr[1] + a.z * xr[2] + a.w * xr[3]
                    + b.x * xr[4] + b.y * xr[5] + b.z * xr[6] + b.w * xr[7];
        }
    }

    float* Yn = Y + (size_t)n * O * L_S;
#pragma unroll
    for (int o = 0; o < 64; ++o) Yn[(size_t)(o0 + o) * L_S + l] = acc[o];
}

// ---------------------------------------------------------------------------
// Depthwise conv k=3, pad=1 along l.  out[n][c][l] = w0*in[l-1]+w1*in[l]+w2*in[l+1]
// grid: (L/256, 3D, N)
// ---------------------------------------------------------------------------
__global__ __launch_bounds__(256) void dwconv(const float* __restrict__ in,
                                              const float* __restrict__ w,
                                              float* __restrict__ out) {
    const int tid = threadIdx.x;
    const int l   = blockIdx.x * 256 + tid;
    const int c   = blockIdx.y;
    const int n   = blockIdx.z;
    const float* row = in + ((size_t)n * C3 + c) * L_S;
    float w0 = w[c * 3 + 0], w1 = w[c * 3 + 1], w2 = w[c * 3 + 2];
    float a = (l > 0)        ? row[l - 1] : 0.f;
    float b = row[l];
    float d = (l < L_S - 1)  ? row[l + 1] : 0.f;
    out[((size_t)n * C3 + c) * L_S + l] = w0 * a + w1 * b + w2 * d;
}

// ---------------------------------------------------------------------------
// L2-normalize q and k along head dim (64 channels per head), in place.
// Channels 0..1023 (q heads 0..7 then k heads 0..7) = 16 groups of 64.
// grid: (L/256, 16, N)
// ---------------------------------------------------------------------------
__global__ __launch_bounds__(256) void l2norm_qk(float* __restrict__ buf) {
    const int tid = threadIdx.x;
    const int l   = blockIdx.x * 256 + tid;
    const int g   = blockIdx.y;
    const int n   = blockIdx.z;
    size_t base = (size_t)n * C3 * L_S + (size_t)g * 64 * L_S + l;
    float v[64];
    float s = 0.f;
#pragma unroll
    for (int e = 0; e < 64; ++e) {
        v[e] = buf[base + (size_t)e * L_S];
        s += v[e] * v[e];
    }
    float scale = 1.0f / fmaxf(sqrtf(s), 1e-12f);
#pragma unroll
    for (int e = 0; e < 64; ++e) buf[base + (size_t)e * L_S] = v[e] * scale;
}

// ---------------------------------------------------------------------------
// Flash attention, fp32 vector. Block = 256 threads (4 waves), 64 queries.
// Per 64-key chunk: K_s[e][68] (lane=j reads consecutive), V_s[j][68]
// (lane=e reads consecutive), q_s[q][68] (b128 broadcast), p_s per-wave
// for the lane-role swap between QK^T (lane=key) and PV (lane=dh elem).
// grid: (L/64, H, N)
// ---------------------------------------------------------------------------
__global__ __launch_bounds__(256) void attn(const float* __restrict__ buf,
                                            const float* __restrict__ temp,
                                            float* __restrict__ out) {
    __shared__ float K_s[64 * 68];
    __shared__ float V_s[64 * 68];
    __shared__ float q_s[64 * 68];
    __shared__ float p_s[4][16 * 64];

    const int tid  = threadIdx.x;
    const int lane = tid & 63;
    const int w    = tid >> 6;
    const int q0   = blockIdx.x * 64;
    const int h    = blockIdx.y;
    const int n    = blockIdx.z;

    const float* Qc = buf + ((size_t)n * C3 + h * DH) * L_S;
    const float* Kc = Qc + (size_t)D_F * L_S;
    const float* Vc = Qc + (size_t)2 * D_F * L_S;
    const float tscale = temp[h];

    // load q tile: 64 q x 64 e -> q_s[q*68 + e]
    for (int f = tid; f < 4096; f += 256) {
        int e = f >> 6, qq = f & 63;
        q_s[qq * 68 + e] = Qc[(size_t)e * L_S + q0 + qq];
    }

    float m[16], lsum[16], acc[16];
#pragma unroll
    for (int q = 0; q < 16; ++q) { m[q] = -1e30f; lsum[q] = 0.f; acc[q] = 0.f; }

    for (int k0 = 0; k0 < L_S; k0 += 64) {
        __syncthreads();   // previous chunk's reads complete before overwrite
        for (int f = tid; f < 4096; f += 256) {
            int e = f >> 6, j = f & 63;
            float kv = Kc[(size_t)e * L_S + k0 + j];
            float vv = Vc[(size_t)e * L_S + k0 + j];
            K_s[e * 68 + j] = kv;
            V_s[j * 68 + e] = vv;
        }
        __syncthreads();

        // ---- scores: lane = key j ----
        float s[16];
#pragma unroll
        for (int q = 0; q < 16; ++q) s[q] = 0.f;
        for (int e4 = 0; e4 < 16; ++e4) {
            float k0v = K_s[(e4 * 4 + 0) * 68 + lane];
            float k1v = K_s[(e4 * 4 + 1) * 68 + lane];
            float k2v = K_s[(e4 * 4 + 2) * 68 + lane];
            float k3v = K_s[(e4 * 4 + 3) * 68 + lane];
#pragma unroll
            for (int q = 0; q < 16; ++q) {
                float4 qv = *(const float4*)&q_s[(w * 16 + q) * 68 + e4 * 4];
                s[q] += qv.x * k0v + qv.y * k1v + qv.z * k2v + qv.w * k3v;
            }
        }

        // ---- online softmax update ----
#pragma unroll
        for (int q = 0; q < 16; ++q) {
            float sv = s[q] * tscale;
            float mx = sv;
#pragma unroll
            for (int off = 32; off; off >>= 1) mx = fmaxf(mx, __shfl_xor(mx, off));
            float mnew = fmaxf(m[q], mx);
            float corr = __expf(m[q] - mnew);
            float p    = __expf(sv - mnew);
            float ps   = p;
#pragma unroll
            for (int off = 32; off; off >>= 1) ps += __shfl_xor(ps, off);
            lsum[q] = lsum[q] * corr + ps;
            acc[q] *= corr;
            m[q] = mnew;
            p_s[w][q * 64 + lane] = p;
        }

        // ---- PV: lane = dh element e ----
        for (int j4 = 0; j4 < 16; ++j4) {
            float v0 = V_s[(j4 * 4 + 0) * 68 + lane];
            float v1 = V_s[(j4 * 4 + 1) * 68 + lane];
            float v2 = V_s[(j4 * 4 + 2) * 68 + lane];
            float v3 = V_s[(j4 * 4 + 3) * 68 + lane];
#pragma unroll
            for (int q = 0; q < 16; ++q) {
                float4 pv = *(const float4*)&p_s[w][q * 64 + j4 * 4];
                acc[q] += pv.x * v0 + pv.y * v1 + pv.z * v2 + pv.w * v3;
            }
        }
    }

    __syncthreads();   // everyone done with K_s -> reuse as transpose stage
#pragma unroll
    for (int q = 0; q < 16; ++q)
        K_s[lane * 68 + w * 16 + q] = acc[q] / lsum[q];   // lane = e
    __syncthreads();

    float* On = out + ((size_t)n * D_F + h * DH) * L_S;
    for (int f = tid; f < 4096; f += 256) {
        int e = f >> 6, qq = f & 63;
        On[(size_t)e * L_S + q0 + qq] = K_s[e * 68 + qq];
    }
}

// ---------------------------------------------------------------------------
extern "C" void kernel_launch(void* const* d_in, const int* in_sizes, int n_in,
                              void* d_out, int out_size, void* d_ws, size_t ws_size,
                              hipStream_t stream) {
    const float* x      = (const float*)d_in[0];   // (4, 512, 2048)
    const float* w_qkv  = (const float*)d_in[1];   // (1536, 512, 1)
    const float* w_dw   = (const float*)d_in[2];   // (1536, 1, 3)
    const float* w_proj = (const float*)d_in[3];   // (512, 512, 1)
    const float* temp   = (const float*)d_in[4];   // (1, 8, 1, 1)
    float* out = (float*)d_out;                    // (4, 512, 2048)

    const size_t QKV_ELEMS = (size_t)N_B * C3 * L_S;   // 12.58M floats
    float* qkv_raw = (float*)d_ws;                     // 48 MB
    float* qkv_dw  = qkv_raw + QKV_ELEMS;              // 48 MB
    float* attn_out = qkv_raw;                         // reuse (16 MB needed)

    // 1) QKV 1x1 conv (GEMM 1536x512 over 8192 columns)
    gemm_ncl<<<dim3(L_S / 256, C3 / 64, N_B), 256, 0, stream>>>(w_qkv, x, qkv_raw, C3, D_F);

    // 2) depthwise conv k=3
    dwconv<<<dim3(L_S / 256, C3, N_B), 256, 0, stream>>>(qkv_raw, w_dw, qkv_dw);

    // 3) l2norm q,k per head (channels 0..1023), in place
    l2norm_qk<<<dim3(L_S / 256, 16, N_B), 256, 0, stream>>>(qkv_dw);

    // 4) attention -> attn_out in (n, d, l) layout
    attn<<<dim3(L_S / 64, H_N, N_B), 256, 0, stream>>>(qkv_dw, temp, attn_out);

    // 5) output projection (GEMM 512x512 over 8192 columns)
    gemm_ncl<<<dim3(L_S / 256, D_F / 64, N_B), 256, 0, stream>>>(w_proj, attn_out, out, D_F, D_F);
}

// Round 2
// 659.912 us; speedup vs baseline: 2.4374x; 2.4374x over previous
//
#include <hip/hip_runtime.h>
#include <hip/hip_bf16.h>
#include <cstdint>
#include <cstddef>

#define N_B 4
#define D_F 512
#define L_S 2048
#define H_N 8
#define DH  64
#define C3  (3*D_F)   // 1536

typedef __attribute__((ext_vector_type(8))) short short8;
typedef __attribute__((ext_vector_type(4))) float f32x4;

__device__ __forceinline__ unsigned int pk_bf16(float a, float b) {
    __hip_bfloat162 h = __float22bfloat162_rn(float2{a, b});
    union { __hip_bfloat162 h; unsigned int u; } cv;
    cv.h = h;
    return cv.u;
}

// ---------------------------------------------------------------------------
// GEMM: Y[n][o][l] = sum_c W[o][c] * X[n][c][l]   (fp32 vector, unchanged)
// ---------------------------------------------------------------------------
__global__ __launch_bounds__(256) void gemm_ncl(const float* __restrict__ W,
                                                const float* __restrict__ X,
                                                float* __restrict__ Y,
                                                int O, int C) {
    __shared__ float w_s[64 * 8];
    const int tid = threadIdx.x;
    const int l   = blockIdx.x * 256 + tid;
    const int o0  = blockIdx.y * 64;
    const int n   = blockIdx.z;
    const float* Xn = X + (size_t)n * C * L_S;

    float acc[64];
#pragma unroll
    for (int i = 0; i < 64; ++i) acc[i] = 0.f;

    for (int c0 = 0; c0 < C; c0 += 8) {
        __syncthreads();
#pragma unroll
        for (int r = 0; r < 2; ++r) {
            int ff = tid + r * 256;
            int oo = ff >> 3, cc = ff & 7;
            w_s[ff] = W[(size_t)(o0 + oo) * C + c0 + cc];
        }
        __syncthreads();

        float xr[8];
#pragma unroll
        for (int j = 0; j < 8; ++j) xr[j] = Xn[(size_t)(c0 + j) * L_S + l];

#pragma unroll
        for (int o = 0; o < 64; ++o) {
            const float4* wp = (const float4*)(&w_s[o * 8]);
            float4 a = wp[0], b = wp[1];
            acc[o] += a.x * xr[0] + a.y * xr[1] + a.z * xr[2] + a.w * xr[3]
                    + b.x * xr[4] + b.y * xr[5] + b.z * xr[6] + b.w * xr[7];
        }
    }

    float* Yn = Y + (size_t)n * O * L_S;
#pragma unroll
    for (int o = 0; o < 64; ++o) Yn[(size_t)(o0 + o) * L_S + l] = acc[o];
}

// ---------------------------------------------------------------------------
// Depthwise conv k=3 (unchanged)
// ---------------------------------------------------------------------------
__global__ __launch_bounds__(256) void dwconv(const float* __restrict__ in,
                                              const float* __restrict__ w,
                                              float* __restrict__ out) {
    const int tid = threadIdx.x;
    const int l   = blockIdx.x * 256 + tid;
    const int c   = blockIdx.y;
    const int n   = blockIdx.z;
    const float* row = in + ((size_t)n * C3 + c) * L_S;
    float w0 = w[c * 3 + 0], w1 = w[c * 3 + 1], w2 = w[c * 3 + 2];
    float a = (l > 0)        ? row[l - 1] : 0.f;
    float b = row[l];
    float d = (l < L_S - 1)  ? row[l + 1] : 0.f;
    out[((size_t)n * C3 + c) * L_S + l] = w0 * a + w1 * b + w2 * d;
}

// ---------------------------------------------------------------------------
// L2-normalize q,k per head (unchanged)
// ---------------------------------------------------------------------------
__global__ __launch_bounds__(256) void l2norm_qk(float* __restrict__ buf) {
    const int tid = threadIdx.x;
    const int l   = blockIdx.x * 256 + tid;
    const int g   = blockIdx.y;
    const int n   = blockIdx.z;
    size_t base = (size_t)n * C3 * L_S + (size_t)g * 64 * L_S + l;
    float v[64];
    float s = 0.f;
#pragma unroll
    for (int e = 0; e < 64; ++e) {
        v[e] = buf[base + (size_t)e * L_S];
        s += v[e] * v[e];
    }
    float scale = 1.0f / fmaxf(sqrtf(s), 1e-12f);
#pragma unroll
    for (int e = 0; e < 64; ++e) buf[base + (size_t)e * L_S] = v[e] * scale;
}

// ---------------------------------------------------------------------------
// Flash attention with bf16 MFMA 16x16x32.
// Block = 256 threads (4 waves) = 64 queries; chunks of 64 keys.
// LDS pack layouts (bf16):
//   Qt/Kt[p][l][i]  : element (e = 8p+i, l)        -> A/B frags along e
//   Vt  [jp][e][jj] : element (e, key = 8jp+jj)    -> B frags along keys
//   Pt  [jp][q][jj] : P[q][key = 8jp+jj]           -> A frags along keys
// MFMA C/D layout: col = lane&15, row = (lane>>4)*4 + reg  [m89-verified]
// A/B layout: row/col = lane&15, k = (lane>>4)*8 + j
// grid: (L/64, H, N)
// ---------------------------------------------------------------------------
__global__ __launch_bounds__(256) void attn_mfma(const float* __restrict__ buf,
                                                 const float* __restrict__ temp,
                                                 float* __restrict__ out) {
    __shared__ unsigned short smem[4 * 4096];   // 32 KB
    unsigned short* Qt = smem;                  // [8][64][8]
    unsigned short* Kt = smem + 4096;
    unsigned short* Vt = smem + 8192;
    unsigned short* Pt = smem + 12288;
    float* Ot = (float*)smem;                   // 64x64 f32, overlaps Qt+Kt

    const int tid  = threadIdx.x;
    const int lane = tid & 63;
    const int w    = tid >> 6;
    const int g    = lane >> 4;
    const int c    = lane & 15;
    const int q0   = blockIdx.x * 64;
    const int h    = blockIdx.y;
    const int n    = blockIdx.z;

    const float* Qc = buf + ((size_t)n * C3 + h * DH) * L_S;
    const float* Kc = Qc + (size_t)D_F * L_S;
    const float* Vc = Qc + (size_t)2 * D_F * L_S;
    const float tscale = temp[h];

    // ---- stage Q once: task (p, qq) reads 8 e's at fixed l (lane-coalesced)
    for (int t = tid; t < 512; t += 256) {
        int p = t >> 6, qq = t & 63;
        const float* src = Qc + (size_t)(8 * p) * L_S + q0 + qq;
        float f[8];
#pragma unroll
        for (int i = 0; i < 8; ++i) f[i] = src[(size_t)i * L_S];
        uint4 pk = make_uint4(pk_bf16(f[0], f[1]), pk_bf16(f[2], f[3]),
                              pk_bf16(f[4], f[5]), pk_bf16(f[6], f[7]));
        *(uint4*)&Qt[p * 512 + qq * 8] = pk;
    }
    __syncthreads();

    short8 qa[2];
    qa[0] = *(short8*)&Qt[(0 + g) * 512 + (w * 16 + c) * 8];
    qa[1] = *(short8*)&Qt[(4 + g) * 512 + (w * 16 + c) * 8];

    f32x4 acc[4];
#pragma unroll
    for (int et = 0; et < 4; ++et) acc[et] = (f32x4){0.f, 0.f, 0.f, 0.f};
    float mrow[4], lrow[4];
#pragma unroll
    for (int r = 0; r < 4; ++r) { mrow[r] = -1e30f; lrow[r] = 0.f; }

    for (int k0 = 0; k0 < L_S; k0 += 64) {
        __syncthreads();    // previous chunk's LDS reads done

        // stage K: e-pack layout
        for (int t = tid; t < 512; t += 256) {
            int p = t >> 6, j = t & 63;
            const float* src = Kc + (size_t)(8 * p) * L_S + k0 + j;
            float f[8];
#pragma unroll
            for (int i = 0; i < 8; ++i) f[i] = src[(size_t)i * L_S];
            uint4 pk = make_uint4(pk_bf16(f[0], f[1]), pk_bf16(f[2], f[3]),
                                  pk_bf16(f[4], f[5]), pk_bf16(f[6], f[7]));
            *(uint4*)&Kt[p * 512 + j * 8] = pk;
        }
        // stage V: key-pack layout (keys contiguous in global -> float4 x2)
        for (int t = tid; t < 512; t += 256) {
            int jp = t >> 6, e = t & 63;
            const float4* src = (const float4*)(Vc + (size_t)e * L_S + k0 + jp * 8);
            float4 v0 = src[0], v1 = src[1];
            uint4 pk = make_uint4(pk_bf16(v0.x, v0.y), pk_bf16(v0.z, v0.w),
                                  pk_bf16(v1.x, v1.y), pk_bf16(v1.z, v1.w));
            *(uint4*)&Vt[jp * 512 + e * 8] = pk;
        }
        __syncthreads();

        // ---- S = Q K^T : wave strip 16q x 64k
        f32x4 sf[4];
#pragma unroll
        for (int kt = 0; kt < 4; ++kt) sf[kt] = (f32x4){0.f, 0.f, 0.f, 0.f};
#pragma unroll
        for (int s = 0; s < 2; ++s) {
#pragma unroll
            for (int kt = 0; kt < 4; ++kt) {
                short8 kb = *(short8*)&Kt[(4 * s + g) * 512 + (kt * 16 + c) * 8];
                sf[kt] = __builtin_amdgcn_mfma_f32_16x16x32_bf16(qa[s], kb, sf[kt], 0, 0, 0);
            }
        }

        // ---- online softmax (fp32); rows r -> q = w*16 + g*4 + r
#pragma unroll
        for (int r = 0; r < 4; ++r) {
            float s0 = sf[0][r] * tscale, s1 = sf[1][r] * tscale;
            float s2 = sf[2][r] * tscale, s3 = sf[3][r] * tscale;
            float mx = fmaxf(fmaxf(s0, s1), fmaxf(s2, s3));
            mx = fmaxf(mx, __shfl_xor(mx, 1));
            mx = fmaxf(mx, __shfl_xor(mx, 2));
            mx = fmaxf(mx, __shfl_xor(mx, 4));
            mx = fmaxf(mx, __shfl_xor(mx, 8));
            float mnew = fmaxf(mrow[r], mx);
            float corr = __expf(mrow[r] - mnew);
            float p0 = __expf(s0 - mnew), p1 = __expf(s1 - mnew);
            float p2 = __expf(s2 - mnew), p3 = __expf(s3 - mnew);
            float ps = p0 + p1 + p2 + p3;
            ps += __shfl_xor(ps, 1);
            ps += __shfl_xor(ps, 2);
            ps += __shfl_xor(ps, 4);
            ps += __shfl_xor(ps, 8);
            lrow[r] = lrow[r] * corr + ps;
            mrow[r] = mnew;
#pragma unroll
            for (int et = 0; et < 4; ++et) acc[et][r] *= corr;

            int q = w * 16 + g * 4 + r;
            // P[q][key] -> Pt[key>>3][q][key&7], key = kt*16 + c
            Pt[((0 * 16 + c) >> 3) * 512 + q * 8 + (c & 7)]        = (unsigned short)(pk_bf16(p0, p0) & 0xFFFF);
            Pt[((1 * 16 + c) >> 3) * 512 + q * 8 + (c & 7)]        = (unsigned short)(pk_bf16(p1, p1) & 0xFFFF);
            Pt[((2 * 16 + c) >> 3) * 512 + q * 8 + (c & 7)]        = (unsigned short)(pk_bf16(p2, p2) & 0xFFFF);
            Pt[((3 * 16 + c) >> 3) * 512 + q * 8 + (c & 7)]        = (unsigned short)(pk_bf16(p3, p3) & 0xFFFF);
        }

        // ---- O += P V : wave strip 16q x 64e (wave-local Pt dependency)
#pragma unroll
        for (int s = 0; s < 2; ++s) {
            short8 pa = *(short8*)&Pt[(4 * s + g) * 512 + (w * 16 + c) * 8];
#pragma unroll
            for (int et = 0; et < 4; ++et) {
                short8 vb = *(short8*)&Vt[(4 * s + g) * 512 + (et * 16 + c) * 8];
                acc[et] = __builtin_amdgcn_mfma_f32_16x16x32_bf16(pa, vb, acc[et], 0, 0, 0);
            }
        }
    }

    __syncthreads();   // all waves done with Qt/Kt -> reuse as Ot
#pragma unroll
    for (int et = 0; et < 4; ++et) {
        int e = et * 16 + c;
#pragma unroll
        for (int r = 0; r < 4; ++r) {
            int q = w * 16 + g * 4 + r;
            Ot[q * 64 + (e ^ (q & 31))] = acc[et][r] / lrow[r];
        }
    }
    __syncthreads();

    float* On = out + ((size_t)n * D_F + h * DH) * L_S;
    for (int t = tid; t < 4096; t += 256) {
        int e = t >> 6, qq = t & 63;
        On[(size_t)e * L_S + q0 + qq] = Ot[qq * 64 + (e ^ (qq & 31))];
    }
}

// ---------------------------------------------------------------------------
extern "C" void kernel_launch(void* const* d_in, const int* in_sizes, int n_in,
                              void* d_out, int out_size, void* d_ws, size_t ws_size,
                              hipStream_t stream) {
    const float* x      = (const float*)d_in[0];
    const float* w_qkv  = (const float*)d_in[1];
    const float* w_dw   = (const float*)d_in[2];
    const float* w_proj = (const float*)d_in[3];
    const float* temp   = (const float*)d_in[4];
    float* out = (float*)d_out;

    const size_t QKV_ELEMS = (size_t)N_B * C3 * L_S;
    float* qkv_raw = (float*)d_ws;
    float* qkv_dw  = qkv_raw + QKV_ELEMS;
    float* attn_out = qkv_raw;   // reuse

    gemm_ncl<<<dim3(L_S / 256, C3 / 64, N_B), 256, 0, stream>>>(w_qkv, x, qkv_raw, C3, D_F);
    dwconv<<<dim3(L_S / 256, C3, N_B), 256, 0, stream>>>(qkv_raw, w_dw, qkv_dw);
    l2norm_qk<<<dim3(L_S / 256, 16, N_B), 256, 0, stream>>>(qkv_dw);
    attn_mfma<<<dim3(L_S / 64, H_N, N_B), 256, 0, stream>>>(qkv_dw, temp, attn_out);
    gemm_ncl<<<dim3(L_S / 256, D_F / 64, N_B), 256, 0, stream>>>(w_proj, attn_out, out, D_F, D_F);
}

// Round 3
// 275.364 us; speedup vs baseline: 5.8413x; 2.3965x over previous
//
#include <hip/hip_runtime.h>
#include <hip/hip_bf16.h>
#include <cstdint>
#include <cstddef>

#define N_B 4
#define D_F 512
#define L_S 2048
#define H_N 8
#define DH  64
#define C3  (3*D_F)   // 1536

typedef __attribute__((ext_vector_type(8))) short short8;
typedef __attribute__((ext_vector_type(4))) float f32x4;

__device__ __forceinline__ unsigned int pk_bf16(float a, float b) {
    __hip_bfloat162 h = __float22bfloat162_rn(float2{a, b});
    union { __hip_bfloat162 h; unsigned int u; } cv;
    cv.h = h;
    return cv.u;
}

__device__ __forceinline__ unsigned short bf16_rn(float f) {
    union { float f; unsigned int u; } c; c.f = f;
    unsigned int r = c.u + 0x7FFF + ((c.u >> 16) & 1);
    return (unsigned short)(r >> 16);
}
__device__ __forceinline__ float bf16_f(unsigned short h) {
    union { unsigned int u; float f; } c; c.u = ((unsigned int)h) << 16;
    return c.f;
}

// ---------------------------------------------------------------------------
// Split a fp32 array into bf16 hi + bf16 lo (lo = rn(x - hi)).
// ---------------------------------------------------------------------------
__global__ __launch_bounds__(256) void cvt_split(const float* __restrict__ src,
                                                 unsigned short* __restrict__ hi,
                                                 unsigned short* __restrict__ lo,
                                                 int n4) {
    int i = blockIdx.x * 256 + threadIdx.x;
    if (i >= n4) return;
    float4 v = ((const float4*)src)[i];
    ushort4 h, l;
    h.x = bf16_rn(v.x); l.x = bf16_rn(v.x - bf16_f(h.x));
    h.y = bf16_rn(v.y); l.y = bf16_rn(v.y - bf16_f(h.y));
    h.z = bf16_rn(v.z); l.z = bf16_rn(v.z - bf16_f(h.z));
    h.w = bf16_rn(v.w); l.w = bf16_rn(v.w - bf16_f(h.w));
    ((ushort4*)hi)[i] = h;
    ((ushort4*)lo)[i] = l;
}

// ---------------------------------------------------------------------------
// MFMA GEMM: Y[n][o][l] = sum_c W[o][c] * X[n][c][l]
// bf16 inputs (hi, + lo when SPLIT for 3-term fp32-ish precision).
// Tile 128o x 128l, BK=32, 4 waves (2x2 of 64x64), 16x16x32 MFMA.
// LDS: Wt/Xt[hi|lo][cp=4][row=128][ci=8]
// grid: (L/128, O/128, N)
// ---------------------------------------------------------------------------
template<int SPLIT, int OUT_BF16>
__global__ __launch_bounds__(256) void gemm_mfma(const unsigned short* __restrict__ Whi,
                                                 const unsigned short* __restrict__ Wlo,
                                                 const unsigned short* __restrict__ Xhi,
                                                 const unsigned short* __restrict__ Xlo,
                                                 void* __restrict__ Y,
                                                 int O, int C) {
    __shared__ unsigned short Wt[SPLIT ? 2 : 1][4][128 * 8];
    __shared__ unsigned short Xt[SPLIT ? 2 : 1][4][128 * 8];

    const int tid  = threadIdx.x;
    const int lane = tid & 63;
    const int w    = tid >> 6;
    const int g    = lane >> 4;
    const int c    = lane & 15;
    const int wr   = (w >> 1) * 64;
    const int wc   = (w & 1) * 64;
    const int l0   = blockIdx.x * 128;
    const int o0   = blockIdx.y * 128;
    const int n    = blockIdx.z;

    const unsigned short* Xn_hi = Xhi + (size_t)n * C * L_S;
    const unsigned short* Xn_lo = SPLIT ? (Xlo + (size_t)n * C * L_S) : nullptr;

    f32x4 acc[4][4];
#pragma unroll
    for (int mt = 0; mt < 4; ++mt)
#pragma unroll
        for (int nt = 0; nt < 4; ++nt) acc[mt][nt] = (f32x4){0.f, 0.f, 0.f, 0.f};

    for (int c0 = 0; c0 < C; c0 += 32) {
        __syncthreads();
        // stage W: task (cp, o) -> one b128 (8 contiguous c's)
#pragma unroll
        for (int t = tid; t < 512; t += 256) {
            int o = t & 127, cp = t >> 7;
            size_t off = (size_t)(o0 + o) * C + c0 + cp * 8;
            *(uint4*)&Wt[0][cp][o * 8] = *(const uint4*)(Whi + off);
            if (SPLIT) *(uint4*)&Wt[1][cp][o * 8] = *(const uint4*)(Wlo + off);
        }
        // stage X: task (cp, l) -> 8 strided u16 reads (lane-coalesced), one b128 write
#pragma unroll
        for (int t = tid; t < 512; t += 256) {
            int l = t & 127, cp = t >> 7;
            const unsigned short* src = Xn_hi + (size_t)(c0 + cp * 8) * L_S + l0 + l;
            short8 v;
#pragma unroll
            for (int i = 0; i < 8; ++i) v[i] = (short)src[(size_t)i * L_S];
            *(short8*)&Xt[0][cp][l * 8] = v;
            if (SPLIT) {
                const unsigned short* srcl = Xn_lo + (size_t)(c0 + cp * 8) * L_S + l0 + l;
                short8 vl;
#pragma unroll
                for (int i = 0; i < 8; ++i) vl[i] = (short)srcl[(size_t)i * L_S];
                *(short8*)&Xt[1][cp][l * 8] = vl;
            }
        }
        __syncthreads();

        short8 a0[4], b0[4];
#pragma unroll
        for (int mt = 0; mt < 4; ++mt) a0[mt] = *(short8*)&Wt[0][g][(wr + mt * 16 + c) * 8];
#pragma unroll
        for (int nt = 0; nt < 4; ++nt) b0[nt] = *(short8*)&Xt[0][g][(wc + nt * 16 + c) * 8];

        if (SPLIT) {
            short8 a1[4], b1[4];
#pragma unroll
            for (int mt = 0; mt < 4; ++mt) a1[mt] = *(short8*)&Wt[1][g][(wr + mt * 16 + c) * 8];
#pragma unroll
            for (int nt = 0; nt < 4; ++nt) b1[nt] = *(short8*)&Xt[1][g][(wc + nt * 16 + c) * 8];
#pragma unroll
            for (int mt = 0; mt < 4; ++mt)
#pragma unroll
                for (int nt = 0; nt < 4; ++nt) {
                    acc[mt][nt] = __builtin_amdgcn_mfma_f32_16x16x32_bf16(a0[mt], b0[nt], acc[mt][nt], 0, 0, 0);
                    acc[mt][nt] = __builtin_amdgcn_mfma_f32_16x16x32_bf16(a0[mt], b1[nt], acc[mt][nt], 0, 0, 0);
                    acc[mt][nt] = __builtin_amdgcn_mfma_f32_16x16x32_bf16(a1[mt], b0[nt], acc[mt][nt], 0, 0, 0);
                }
        } else {
#pragma unroll
            for (int mt = 0; mt < 4; ++mt)
#pragma unroll
                for (int nt = 0; nt < 4; ++nt)
                    acc[mt][nt] = __builtin_amdgcn_mfma_f32_16x16x32_bf16(a0[mt], b0[nt], acc[mt][nt], 0, 0, 0);
        }
    }

    // epilogue: C/D layout col(l)=lane&15, row(o)=(lane>>4)*4+r
#pragma unroll
    for (int mt = 0; mt < 4; ++mt) {
#pragma unroll
        for (int r = 0; r < 4; ++r) {
            int oo = o0 + wr + mt * 16 + g * 4 + r;
            size_t rowbase = ((size_t)n * O + oo) * L_S;
#pragma unroll
            for (int nt = 0; nt < 4; ++nt) {
                int ll = l0 + wc + nt * 16 + c;
                if (OUT_BF16)
                    ((unsigned short*)Y)[rowbase + ll] = bf16_rn(acc[mt][nt][r]);
                else
                    ((float*)Y)[rowbase + ll] = acc[mt][nt][r];
            }
        }
    }
}

// ---------------------------------------------------------------------------
// Depthwise conv k=3, pad=1; bf16 input, fp32 output.
// ---------------------------------------------------------------------------
__global__ __launch_bounds__(256) void dwconv(const unsigned short* __restrict__ in,
                                              const float* __restrict__ w,
                                              float* __restrict__ out) {
    const int tid = threadIdx.x;
    const int l   = blockIdx.x * 256 + tid;
    const int ch  = blockIdx.y;
    const int n   = blockIdx.z;
    const unsigned short* row = in + ((size_t)n * C3 + ch) * L_S;
    float w0 = w[ch * 3 + 0], w1 = w[ch * 3 + 1], w2 = w[ch * 3 + 2];
    float a = (l > 0)       ? bf16_f(row[l - 1]) : 0.f;
    float b = bf16_f(row[l]);
    float d = (l < L_S - 1) ? bf16_f(row[l + 1]) : 0.f;
    out[((size_t)n * C3 + ch) * L_S + l] = w0 * a + w1 * b + w2 * d;
}

// ---------------------------------------------------------------------------
// L2-normalize q,k per head (fp32, in place).
// ---------------------------------------------------------------------------
__global__ __launch_bounds__(256) void l2norm_qk(float* __restrict__ buf) {
    const int tid = threadIdx.x;
    const int l   = blockIdx.x * 256 + tid;
    const int g   = blockIdx.y;
    const int n   = blockIdx.z;
    size_t base = (size_t)n * C3 * L_S + (size_t)g * 64 * L_S + l;
    float v[64];
    float s = 0.f;
#pragma unroll
    for (int e = 0; e < 64; ++e) {
        v[e] = buf[base + (size_t)e * L_S];
        s += v[e] * v[e];
    }
    float scale = 1.0f / fmaxf(sqrtf(s), 1e-12f);
#pragma unroll
    for (int e = 0; e < 64; ++e) buf[base + (size_t)e * L_S] = v[e] * scale;
}

// ---------------------------------------------------------------------------
// Flash attention with bf16 MFMA 16x16x32 (unchanged from R2).
// grid: (L/64, H, N)
// ---------------------------------------------------------------------------
__global__ __launch_bounds__(256) void attn_mfma(const float* __restrict__ buf,
                                                 const float* __restrict__ temp,
                                                 float* __restrict__ out) {
    __shared__ unsigned short smem[4 * 4096];   // 32 KB
    unsigned short* Qt = smem;                  // [8][64][8]
    unsigned short* Kt = smem + 4096;
    unsigned short* Vt = smem + 8192;
    unsigned short* Pt = smem + 12288;
    float* Ot = (float*)smem;

    const int tid  = threadIdx.x;
    const int lane = tid & 63;
    const int w    = tid >> 6;
    const int g    = lane >> 4;
    const int c    = lane & 15;
    const int q0   = blockIdx.x * 64;
    const int h    = blockIdx.y;
    const int n    = blockIdx.z;

    const float* Qc = buf + ((size_t)n * C3 + h * DH) * L_S;
    const float* Kc = Qc + (size_t)D_F * L_S;
    const float* Vc = Qc + (size_t)2 * D_F * L_S;
    const float tscale = temp[h];

    for (int t = tid; t < 512; t += 256) {
        int p = t >> 6, qq = t & 63;
        const float* src = Qc + (size_t)(8 * p) * L_S + q0 + qq;
        float f[8];
#pragma unroll
        for (int i = 0; i < 8; ++i) f[i] = src[(size_t)i * L_S];
        uint4 pk = make_uint4(pk_bf16(f[0], f[1]), pk_bf16(f[2], f[3]),
                              pk_bf16(f[4], f[5]), pk_bf16(f[6], f[7]));
        *(uint4*)&Qt[p * 512 + qq * 8] = pk;
    }
    __syncthreads();

    short8 qa[2];
    qa[0] = *(short8*)&Qt[(0 + g) * 512 + (w * 16 + c) * 8];
    qa[1] = *(short8*)&Qt[(4 + g) * 512 + (w * 16 + c) * 8];

    f32x4 acc[4];
#pragma unroll
    for (int et = 0; et < 4; ++et) acc[et] = (f32x4){0.f, 0.f, 0.f, 0.f};
    float mrow[4], lrow[4];
#pragma unroll
    for (int r = 0; r < 4; ++r) { mrow[r] = -1e30f; lrow[r] = 0.f; }

    for (int k0 = 0; k0 < L_S; k0 += 64) {
        __syncthreads();
        for (int t = tid; t < 512; t += 256) {
            int p = t >> 6, j = t & 63;
            const float* src = Kc + (size_t)(8 * p) * L_S + k0 + j;
            float f[8];
#pragma unroll
            for (int i = 0; i < 8; ++i) f[i] = src[(size_t)i * L_S];
            uint4 pk = make_uint4(pk_bf16(f[0], f[1]), pk_bf16(f[2], f[3]),
                                  pk_bf16(f[4], f[5]), pk_bf16(f[6], f[7]));
            *(uint4*)&Kt[p * 512 + j * 8] = pk;
        }
        for (int t = tid; t < 512; t += 256) {
            int jp = t >> 6, e = t & 63;
            const float4* src = (const float4*)(Vc + (size_t)e * L_S + k0 + jp * 8);
            float4 v0 = src[0], v1 = src[1];
            uint4 pk = make_uint4(pk_bf16(v0.x, v0.y), pk_bf16(v0.z, v0.w),
                                  pk_bf16(v1.x, v1.y), pk_bf16(v1.z, v1.w));
            *(uint4*)&Vt[jp * 512 + e * 8] = pk;
        }
        __syncthreads();

        f32x4 sf[4];
#pragma unroll
        for (int kt = 0; kt < 4; ++kt) sf[kt] = (f32x4){0.f, 0.f, 0.f, 0.f};
#pragma unroll
        for (int s = 0; s < 2; ++s) {
#pragma unroll
            for (int kt = 0; kt < 4; ++kt) {
                short8 kb = *(short8*)&Kt[(4 * s + g) * 512 + (kt * 16 + c) * 8];
                sf[kt] = __builtin_amdgcn_mfma_f32_16x16x32_bf16(qa[s], kb, sf[kt], 0, 0, 0);
            }
        }

#pragma unroll
        for (int r = 0; r < 4; ++r) {
            float s0 = sf[0][r] * tscale, s1 = sf[1][r] * tscale;
            float s2 = sf[2][r] * tscale, s3 = sf[3][r] * tscale;
            float mx = fmaxf(fmaxf(s0, s1), fmaxf(s2, s3));
            mx = fmaxf(mx, __shfl_xor(mx, 1));
            mx = fmaxf(mx, __shfl_xor(mx, 2));
            mx = fmaxf(mx, __shfl_xor(mx, 4));
            mx = fmaxf(mx, __shfl_xor(mx, 8));
            float mnew = fmaxf(mrow[r], mx);
            float corr = __expf(mrow[r] - mnew);
            float p0 = __expf(s0 - mnew), p1 = __expf(s1 - mnew);
            float p2 = __expf(s2 - mnew), p3 = __expf(s3 - mnew);
            float ps = p0 + p1 + p2 + p3;
            ps += __shfl_xor(ps, 1);
            ps += __shfl_xor(ps, 2);
            ps += __shfl_xor(ps, 4);
            ps += __shfl_xor(ps, 8);
            lrow[r] = lrow[r] * corr + ps;
            mrow[r] = mnew;
#pragma unroll
            for (int et = 0; et < 4; ++et) acc[et][r] *= corr;

            int q = w * 16 + g * 4 + r;
            Pt[((0 * 16 + c) >> 3) * 512 + q * 8 + (c & 7)] = (unsigned short)(pk_bf16(p0, p0) & 0xFFFF);
            Pt[((1 * 16 + c) >> 3) * 512 + q * 8 + (c & 7)] = (unsigned short)(pk_bf16(p1, p1) & 0xFFFF);
            Pt[((2 * 16 + c) >> 3) * 512 + q * 8 + (c & 7)] = (unsigned short)(pk_bf16(p2, p2) & 0xFFFF);
            Pt[((3 * 16 + c) >> 3) * 512 + q * 8 + (c & 7)] = (unsigned short)(pk_bf16(p3, p3) & 0xFFFF);
        }

#pragma unroll
        for (int s = 0; s < 2; ++s) {
            short8 pa = *(short8*)&Pt[(4 * s + g) * 512 + (w * 16 + c) * 8];
#pragma unroll
            for (int et = 0; et < 4; ++et) {
                short8 vb = *(short8*)&Vt[(4 * s + g) * 512 + (et * 16 + c) * 8];
                acc[et] = __builtin_amdgcn_mfma_f32_16x16x32_bf16(pa, vb, acc[et], 0, 0, 0);
            }
        }
    }

    __syncthreads();
#pragma unroll
    for (int et = 0; et < 4; ++et) {
        int e = et * 16 + c;
#pragma unroll
        for (int r = 0; r < 4; ++r) {
            int q = w * 16 + g * 4 + r;
            Ot[q * 64 + (e ^ (q & 31))] = acc[et][r] / lrow[r];
        }
    }
    __syncthreads();

    float* On = out + ((size_t)n * D_F + h * DH) * L_S;
    for (int t = tid; t < 4096; t += 256) {
        int e = t >> 6, qq = t & 63;
        On[(size_t)e * L_S + q0 + qq] = Ot[qq * 64 + (e ^ (qq & 31))];
    }
}

// ---------------------------------------------------------------------------
extern "C" void kernel_launch(void* const* d_in, const int* in_sizes, int n_in,
                              void* d_out, int out_size, void* d_ws, size_t ws_size,
                              hipStream_t stream) {
    const float* x      = (const float*)d_in[0];   // (4, 512, 2048)
    const float* w_qkv  = (const float*)d_in[1];   // (1536, 512)
    const float* w_dw   = (const float*)d_in[2];   // (1536, 3)
    const float* w_proj = (const float*)d_in[3];   // (512, 512)
    const float* temp   = (const float*)d_in[4];   // (8)
    float* out = (float*)d_out;                    // (4, 512, 2048)

    const size_t XE   = (size_t)N_B * D_F * L_S;   // 4,194,304
    const size_t WQE  = (size_t)C3 * D_F;          // 786,432
    const size_t WPE  = (size_t)D_F * D_F;         // 262,144

    char* ws = (char*)d_ws;
    unsigned short* qkv_bf = (unsigned short*)ws;                    // 25,165,824 B
    float*          qkv_dw = (float*)(ws + 25165824);                // 50,331,648 B
    unsigned short* x_hi   = (unsigned short*)(ws + 75497472);       //  8,388,608 B
    unsigned short* x_lo   = (unsigned short*)(ws + 83886080);       //  8,388,608 B
    unsigned short* wq_hi  = (unsigned short*)(ws + 92274688);       //  1,572,864 B
    unsigned short* wq_lo  = wq_hi + WQE;
    unsigned short* wp_hi  = wq_lo + WQE;
    unsigned short* wp_lo  = wp_hi + WPE;                            // ends ~96.5 MB
    float* attn_out = (float*)ws;            // reuse qkv_bf region (16.8 <= 25.2 MB)
    unsigned short* ao_hi = x_hi;            // reuse x split region
    unsigned short* ao_lo = x_lo;

    // 0) precision splits
    cvt_split<<<dim3((XE / 4 + 255) / 256), 256, 0, stream>>>(x, x_hi, x_lo, XE / 4);
    cvt_split<<<dim3((WQE / 4 + 255) / 256), 256, 0, stream>>>(w_qkv, wq_hi, wq_lo, WQE / 4);
    cvt_split<<<dim3((WPE / 4 + 255) / 256), 256, 0, stream>>>(w_proj, wp_hi, wp_lo, WPE / 4);

    // 1) QKV 1x1 conv: plain bf16 MFMA, bf16 out
    gemm_mfma<0, 1><<<dim3(L_S / 128, C3 / 128, N_B), 256, 0, stream>>>(
        wq_hi, nullptr, x_hi, nullptr, qkv_bf, C3, D_F);

    // 2) depthwise conv (bf16 in, fp32 out)
    dwconv<<<dim3(L_S / 256, C3, N_B), 256, 0, stream>>>(qkv_bf, w_dw, qkv_dw);

    // 3) l2norm q,k per head
    l2norm_qk<<<dim3(L_S / 256, 16, N_B), 256, 0, stream>>>(qkv_dw);

    // 4) attention -> attn_out (n, d, l) fp32
    attn_mfma<<<dim3(L_S / 64, H_N, N_B), 256, 0, stream>>>(qkv_dw, temp, attn_out);

    // 5) split attn_out, then 3-term split-bf16 proj GEMM -> fp32 out
    cvt_split<<<dim3((XE / 4 + 255) / 256), 256, 0, stream>>>(attn_out, ao_hi, ao_lo, XE / 4);
    gemm_mfma<1, 0><<<dim3(L_S / 128, D_F / 128, N_B), 256, 0, stream>>>(
        wp_hi, wp_lo, ao_hi, ao_lo, out, D_F, D_F);
}

// Round 4
// 255.920 us; speedup vs baseline: 6.2851x; 1.0760x over previous
//
#include <hip/hip_runtime.h>
#include <hip/hip_bf16.h>
#include <cstdint>
#include <cstddef>

#define N_B 4
#define D_F 512
#define L_S 2048
#define H_N 8
#define DH  64
#define C3  (3*D_F)   // 1536

typedef __attribute__((ext_vector_type(8))) short short8;
typedef __attribute__((ext_vector_type(4))) float f32x4;

__device__ __forceinline__ unsigned int pk_bf16(float a, float b) {
    __hip_bfloat162 h = __float22bfloat162_rn(float2{a, b});
    union { __hip_bfloat162 h; unsigned int u; } cv;
    cv.h = h;
    return cv.u;
}
__device__ __forceinline__ unsigned short bf16_rn(float f) {
    union { float f; unsigned int u; } c; c.f = f;
    unsigned int r = c.u + 0x7FFF + ((c.u >> 16) & 1);
    return (unsigned short)(r >> 16);
}
__device__ __forceinline__ float bf16_f(unsigned short h) {
    union { unsigned int u; float f; } c; c.u = ((unsigned int)h) << 16;
    return c.f;
}

// ---------------------------------------------------------------------------
// Split fp32 -> bf16 hi + bf16 lo
// ---------------------------------------------------------------------------
__global__ __launch_bounds__(256) void cvt_split(const float* __restrict__ src,
                                                 unsigned short* __restrict__ hi,
                                                 unsigned short* __restrict__ lo,
                                                 int n4) {
    int i = blockIdx.x * 256 + threadIdx.x;
    if (i >= n4) return;
    float4 v = ((const float4*)src)[i];
    ushort4 h, l;
    h.x = bf16_rn(v.x); l.x = bf16_rn(v.x - bf16_f(h.x));
    h.y = bf16_rn(v.y); l.y = bf16_rn(v.y - bf16_f(h.y));
    h.z = bf16_rn(v.z); l.z = bf16_rn(v.z - bf16_f(h.z));
    h.w = bf16_rn(v.w); l.w = bf16_rn(v.w - bf16_f(h.w));
    ((ushort4*)hi)[i] = h;
    ((ushort4*)lo)[i] = l;
}

// ---------------------------------------------------------------------------
// MFMA GEMM (unchanged from R3): Y[n][o][l] = sum_c W[o][c] * X[n][c][l]
// ---------------------------------------------------------------------------
template<int SPLIT, int OUT_BF16>
__global__ __launch_bounds__(256) void gemm_mfma(const unsigned short* __restrict__ Whi,
                                                 const unsigned short* __restrict__ Wlo,
                                                 const unsigned short* __restrict__ Xhi,
                                                 const unsigned short* __restrict__ Xlo,
                                                 void* __restrict__ Y,
                                                 int O, int C) {
    __shared__ unsigned short Wt[SPLIT ? 2 : 1][4][128 * 8];
    __shared__ unsigned short Xt[SPLIT ? 2 : 1][4][128 * 8];

    const int tid  = threadIdx.x;
    const int lane = tid & 63;
    const int w    = tid >> 6;
    const int g    = lane >> 4;
    const int c    = lane & 15;
    const int wr   = (w >> 1) * 64;
    const int wc   = (w & 1) * 64;
    const int l0   = blockIdx.x * 128;
    const int o0   = blockIdx.y * 128;
    const int n    = blockIdx.z;

    const unsigned short* Xn_hi = Xhi + (size_t)n * C * L_S;
    const unsigned short* Xn_lo = SPLIT ? (Xlo + (size_t)n * C * L_S) : nullptr;

    f32x4 acc[4][4];
#pragma unroll
    for (int mt = 0; mt < 4; ++mt)
#pragma unroll
        for (int nt = 0; nt < 4; ++nt) acc[mt][nt] = (f32x4){0.f, 0.f, 0.f, 0.f};

    for (int c0 = 0; c0 < C; c0 += 32) {
        __syncthreads();
#pragma unroll
        for (int t = tid; t < 512; t += 256) {
            int o = t & 127, cp = t >> 7;
            size_t off = (size_t)(o0 + o) * C + c0 + cp * 8;
            *(uint4*)&Wt[0][cp][o * 8] = *(const uint4*)(Whi + off);
            if (SPLIT) *(uint4*)&Wt[1][cp][o * 8] = *(const uint4*)(Wlo + off);
        }
#pragma unroll
        for (int t = tid; t < 512; t += 256) {
            int l = t & 127, cp = t >> 7;
            const unsigned short* src = Xn_hi + (size_t)(c0 + cp * 8) * L_S + l0 + l;
            short8 v;
#pragma unroll
            for (int i = 0; i < 8; ++i) v[i] = (short)src[(size_t)i * L_S];
            *(short8*)&Xt[0][cp][l * 8] = v;
            if (SPLIT) {
                const unsigned short* srcl = Xn_lo + (size_t)(c0 + cp * 8) * L_S + l0 + l;
                short8 vl;
#pragma unroll
                for (int i = 0; i < 8; ++i) vl[i] = (short)srcl[(size_t)i * L_S];
                *(short8*)&Xt[1][cp][l * 8] = vl;
            }
        }
        __syncthreads();

        short8 a0[4], b0[4];
#pragma unroll
        for (int mt = 0; mt < 4; ++mt) a0[mt] = *(short8*)&Wt[0][g][(wr + mt * 16 + c) * 8];
#pragma unroll
        for (int nt = 0; nt < 4; ++nt) b0[nt] = *(short8*)&Xt[0][g][(wc + nt * 16 + c) * 8];

        if (SPLIT) {
            short8 a1[4], b1[4];
#pragma unroll
            for (int mt = 0; mt < 4; ++mt) a1[mt] = *(short8*)&Wt[1][g][(wr + mt * 16 + c) * 8];
#pragma unroll
            for (int nt = 0; nt < 4; ++nt) b1[nt] = *(short8*)&Xt[1][g][(wc + nt * 16 + c) * 8];
#pragma unroll
            for (int mt = 0; mt < 4; ++mt)
#pragma unroll
                for (int nt = 0; nt < 4; ++nt) {
                    acc[mt][nt] = __builtin_amdgcn_mfma_f32_16x16x32_bf16(a0[mt], b0[nt], acc[mt][nt], 0, 0, 0);
                    acc[mt][nt] = __builtin_amdgcn_mfma_f32_16x16x32_bf16(a0[mt], b1[nt], acc[mt][nt], 0, 0, 0);
                    acc[mt][nt] = __builtin_amdgcn_mfma_f32_16x16x32_bf16(a1[mt], b0[nt], acc[mt][nt], 0, 0, 0);
                }
        } else {
#pragma unroll
            for (int mt = 0; mt < 4; ++mt)
#pragma unroll
                for (int nt = 0; nt < 4; ++nt)
                    acc[mt][nt] = __builtin_amdgcn_mfma_f32_16x16x32_bf16(a0[mt], b0[nt], acc[mt][nt], 0, 0, 0);
        }
    }

#pragma unroll
    for (int mt = 0; mt < 4; ++mt) {
#pragma unroll
        for (int r = 0; r < 4; ++r) {
            int oo = o0 + wr + mt * 16 + g * 4 + r;
            size_t rowbase = ((size_t)n * O + oo) * L_S;
#pragma unroll
            for (int nt = 0; nt < 4; ++nt) {
                int ll = l0 + wc + nt * 16 + c;
                if (OUT_BF16)
                    ((unsigned short*)Y)[rowbase + ll] = bf16_rn(acc[mt][nt][r]);
                else
                    ((float*)Y)[rowbase + ll] = acc[mt][nt][r];
            }
        }
    }
}

// ---------------------------------------------------------------------------
// Fused dwconv + l2norm + bf16 pack for Q and K heads.
// grid: (L/256, 16, N); gg<8 -> q head gg (ch gg*64), gg>=8 -> k head gg-8.
// Output layout Qb/Kb[n][h][p=e>>3][l][i=e&7] (planes of 1KB-contiguous rows).
// ---------------------------------------------------------------------------
__global__ __launch_bounds__(256) void fused_qk(const unsigned short* __restrict__ qkv_bf,
                                                const float* __restrict__ w_dw,
                                                unsigned short* __restrict__ Qb,
                                                unsigned short* __restrict__ Kb) {
    __shared__ float wsm[192];
    const int tid = threadIdx.x;
    const int l   = blockIdx.x * 256 + tid;
    const int gg  = blockIdx.y;
    const int n   = blockIdx.z;
    const int head = gg & 7;
    const int ch0  = (gg < 8) ? head * 64 : 512 + head * 64;

    if (tid < 192) wsm[tid] = w_dw[ch0 * 3 + tid];
    __syncthreads();

    const unsigned short* base = qkv_bf + ((size_t)n * C3 + ch0) * L_S;
    float y[64];
    float s = 0.f;
#pragma unroll
    for (int e = 0; e < 64; ++e) {
        const unsigned short* row = base + (size_t)e * L_S + l;
        float a = (l > 0)       ? bf16_f(row[-1]) : 0.f;
        float b = bf16_f(row[0]);
        float d = (l < L_S - 1) ? bf16_f(row[1])  : 0.f;
        float v = wsm[e * 3 + 0] * a + wsm[e * 3 + 1] * b + wsm[e * 3 + 2] * d;
        y[e] = v;
        s += v * v;
    }
    float sc = 1.0f / fmaxf(sqrtf(s), 1e-12f);

    unsigned short* dst = ((gg < 8) ? Qb : Kb) + (size_t)(n * H_N + head) * 8 * L_S * 8;
#pragma unroll
    for (int p = 0; p < 8; ++p) {
        uint4 pk = make_uint4(pk_bf16(y[8 * p + 0] * sc, y[8 * p + 1] * sc),
                              pk_bf16(y[8 * p + 2] * sc, y[8 * p + 3] * sc),
                              pk_bf16(y[8 * p + 4] * sc, y[8 * p + 5] * sc),
                              pk_bf16(y[8 * p + 6] * sc, y[8 * p + 7] * sc));
        *(uint4*)&dst[((size_t)p * L_S + l) * 8] = pk;
    }
}

// ---------------------------------------------------------------------------
// Fused dwconv + bf16 pack for V heads.
// grid: (L/64, H, N), 256 threads = 64 keys x 4 channel-groups.
// Output layout Vb[n][h][jp=key>>3][e][jj=key&7].
// ---------------------------------------------------------------------------
__global__ __launch_bounds__(256) void fused_v(const unsigned short* __restrict__ qkv_bf,
                                               const float* __restrict__ w_dw,
                                               unsigned short* __restrict__ Vb) {
    const int tid = threadIdx.x;
    const int j   = tid & 63;
    const int eg  = tid >> 6;
    const int k0  = blockIdx.x * 64;
    const int h   = blockIdx.y;
    const int n   = blockIdx.z;
    const int key = k0 + j;
    const int ch0 = 1024 + h * 64 + eg * 16;

    size_t vb_base = ((size_t)(n * H_N + h) * 256 + (key >> 3)) * 512 + (key & 7);
#pragma unroll
    for (int ee = 0; ee < 16; ++ee) {
        int ch = ch0 + ee;
        const unsigned short* row = qkv_bf + ((size_t)n * C3 + ch) * L_S + key;
        float a = (key > 0)       ? bf16_f(row[-1]) : 0.f;
        float b = bf16_f(row[0]);
        float d = (key < L_S - 1) ? bf16_f(row[1])  : 0.f;
        float v = w_dw[ch * 3 + 0] * a + w_dw[ch * 3 + 1] * b + w_dw[ch * 3 + 2] * d;
        Vb[vb_base + (size_t)(eg * 16 + ee) * 8] = bf16_rn(v);
    }
}

// ---------------------------------------------------------------------------
// Flash attention v2: pre-packed bf16 inputs, fixed-max softmax (exact:
// |score| <= |t| since ||q||=||k||=1), lane-local p-sums, hi/lo bf16 output.
// grid: (L/64, H, N), 4 waves x 16 queries.
// ---------------------------------------------------------------------------
__global__ __launch_bounds__(256) void attn2(const unsigned short* __restrict__ Qb,
                                             const unsigned short* __restrict__ Kb,
                                             const unsigned short* __restrict__ Vb,
                                             const float* __restrict__ temp,
                                             unsigned short* __restrict__ ao_hi,
                                             unsigned short* __restrict__ ao_lo) {
    __shared__ unsigned short smem[4 * 4096];   // 32 KB
    unsigned short* Qt = smem;                  // [8][64][8]
    unsigned short* Kt = smem + 4096;
    unsigned short* Vt = smem + 8192;           // [8 jp][64 e][8]
    unsigned short* Pt = smem + 12288;          // [8 jp][64 q][8]
    float* Ot = (float*)smem;                   // 64x64 f32 overlay on Qt+Kt

    const int tid  = threadIdx.x;
    const int lane = tid & 63;
    const int w    = tid >> 6;
    const int g    = lane >> 4;
    const int c    = lane & 15;
    const int q0   = blockIdx.x * 64;
    const int h    = blockIdx.y;
    const int n    = blockIdx.z;

    const size_t hb = (size_t)(n * H_N + h);
    const unsigned short* Qh = Qb + hb * 8 * L_S * 8;
    const unsigned short* Kh = Kb + hb * 8 * L_S * 8;
    const unsigned short* Vh = Vb + hb * 256 * 512;
    const float t    = temp[h];
    const float negm = -fabsf(t);

    // stage Q (once)
    for (int tt = tid; tt < 512; tt += 256) {
        int p = tt >> 6, lq = tt & 63;
        *(uint4*)&Qt[p * 512 + lq * 8] = *(const uint4*)&Qh[((size_t)p * L_S + q0 + lq) * 8];
    }
    __syncthreads();
    short8 qa[2];
    qa[0] = *(short8*)&Qt[(0 + g) * 512 + (w * 16 + c) * 8];
    qa[1] = *(short8*)&Qt[(4 + g) * 512 + (w * 16 + c) * 8];

    f32x4 acc[4];
#pragma unroll
    for (int et = 0; et < 4; ++et) acc[et] = (f32x4){0.f, 0.f, 0.f, 0.f};
    float sumP[4] = {0.f, 0.f, 0.f, 0.f};

    for (int k0 = 0; k0 < L_S; k0 += 64) {
        __syncthreads();
        for (int tt = tid; tt < 512; tt += 256) {
            int p = tt >> 6, j = tt & 63;
            *(uint4*)&Kt[p * 512 + j * 8] = *(const uint4*)&Kh[((size_t)p * L_S + k0 + j) * 8];
        }
        const int jp0 = k0 >> 3;
        for (int tt = tid; tt < 512; tt += 256) {
            int pp = tt >> 6, e = tt & 63;
            *(uint4*)&Vt[pp * 512 + e * 8] = *(const uint4*)&Vh[(size_t)(jp0 + pp) * 512 + e * 8];
        }
        __syncthreads();

        // S = Q K^T
        f32x4 sf[4];
#pragma unroll
        for (int kt = 0; kt < 4; ++kt) sf[kt] = (f32x4){0.f, 0.f, 0.f, 0.f};
#pragma unroll
        for (int s = 0; s < 2; ++s) {
#pragma unroll
            for (int kt = 0; kt < 4; ++kt) {
                short8 kb = *(short8*)&Kt[(4 * s + g) * 512 + (kt * 16 + c) * 8];
                sf[kt] = __builtin_amdgcn_mfma_f32_16x16x32_bf16(qa[s], kb, sf[kt], 0, 0, 0);
            }
        }

        // fixed-max softmax: p = exp(s*t - |t|); lane-local sums
#pragma unroll
        for (int r = 0; r < 4; ++r) {
            float p0 = __expf(fmaf(sf[0][r], t, negm));
            float p1 = __expf(fmaf(sf[1][r], t, negm));
            float p2 = __expf(fmaf(sf[2][r], t, negm));
            float p3 = __expf(fmaf(sf[3][r], t, negm));
            sumP[r] += (p0 + p1) + (p2 + p3);
            int q = w * 16 + g * 4 + r;
            // P[q][key=kt*16+c] -> Pt[kt*2 + (c>>3)][q][c&7]
            Pt[(0 + (c >> 3)) * 512 + q * 8 + (c & 7)] = bf16_rn(p0);
            Pt[(2 + (c >> 3)) * 512 + q * 8 + (c & 7)] = bf16_rn(p1);
            Pt[(4 + (c >> 3)) * 512 + q * 8 + (c & 7)] = bf16_rn(p2);
            Pt[(6 + (c >> 3)) * 512 + q * 8 + (c & 7)] = bf16_rn(p3);
        }

        // O += P V   (Pt rows are wave-local; in-wave LDS ordering suffices)
#pragma unroll
        for (int s = 0; s < 2; ++s) {
            short8 pa = *(short8*)&Pt[(4 * s + g) * 512 + (w * 16 + c) * 8];
#pragma unroll
            for (int et = 0; et < 4; ++et) {
                short8 vb = *(short8*)&Vt[(4 * s + g) * 512 + (et * 16 + c) * 8];
                acc[et] = __builtin_amdgcn_mfma_f32_16x16x32_bf16(pa, vb, acc[et], 0, 0, 0);
            }
        }
    }

    // final denominator reduce (once)
    float inv[4];
#pragma unroll
    for (int r = 0; r < 4; ++r) {
        float ps = sumP[r];
        ps += __shfl_xor(ps, 1);
        ps += __shfl_xor(ps, 2);
        ps += __shfl_xor(ps, 4);
        ps += __shfl_xor(ps, 8);
        inv[r] = 1.0f / ps;
    }

    __syncthreads();
#pragma unroll
    for (int et = 0; et < 4; ++et) {
        int e = et * 16 + c;
#pragma unroll
        for (int r = 0; r < 4; ++r) {
            int q = w * 16 + g * 4 + r;
            Ot[q * 64 + (e ^ (q & 31))] = acc[et][r] * inv[r];
        }
    }
    __syncthreads();

    for (int tt = tid; tt < 4096; tt += 256) {
        int e = tt >> 6, qq = tt & 63;
        float v = Ot[qq * 64 + (e ^ (qq & 31))];
        unsigned short hi_ = bf16_rn(v);
        unsigned short lo_ = bf16_rn(v - bf16_f(hi_));
        size_t off = ((size_t)n * D_F + h * 64 + e) * L_S + q0 + qq;
        ao_hi[off] = hi_;
        ao_lo[off] = lo_;
    }
}

// ---------------------------------------------------------------------------
extern "C" void kernel_launch(void* const* d_in, const int* in_sizes, int n_in,
                              void* d_out, int out_size, void* d_ws, size_t ws_size,
                              hipStream_t stream) {
    const float* x      = (const float*)d_in[0];   // (4, 512, 2048)
    const float* w_qkv  = (const float*)d_in[1];   // (1536, 512)
    const float* w_dw   = (const float*)d_in[2];   // (1536, 3)
    const float* w_proj = (const float*)d_in[3];   // (512, 512)
    const float* temp   = (const float*)d_in[4];   // (8)
    float* out = (float*)d_out;

    const size_t XE  = (size_t)N_B * D_F * L_S;    // 4,194,304
    const size_t WQE = (size_t)C3 * D_F;           // 786,432
    const size_t WPE = (size_t)D_F * D_F;          // 262,144

    char* ws = (char*)d_ws;
    unsigned short* qkv_bf = (unsigned short*)ws;               // 25,165,824 B
    unsigned short* Qb     = (unsigned short*)(ws + 25165824);  //  8,388,608 B
    unsigned short* Kb     = (unsigned short*)(ws + 33554432);  //  8,388,608 B
    unsigned short* Vb     = (unsigned short*)(ws + 41943040);  //  8,388,608 B
    unsigned short* x_hi   = (unsigned short*)(ws + 50331648);  //  8,388,608 B
    unsigned short* x_lo   = (unsigned short*)(ws + 58720256);  //  8,388,608 B
    unsigned short* wq_hi  = (unsigned short*)(ws + 67108864);  //  1,572,864 B
    unsigned short* wq_lo  = wq_hi + WQE;
    unsigned short* wp_hi  = (unsigned short*)(ws + 70254592);  //    524,288 B
    unsigned short* wp_lo  = wp_hi + WPE;                       // ends ~71.3 MB
    unsigned short* ao_hi  = x_hi;   // reuse (x consumed by QKV gemm)
    unsigned short* ao_lo  = x_lo;

    // 0) precision splits
    cvt_split<<<dim3((XE / 4 + 255) / 256), 256, 0, stream>>>(x, x_hi, x_lo, XE / 4);
    cvt_split<<<dim3((WQE / 4 + 255) / 256), 256, 0, stream>>>(w_qkv, wq_hi, wq_lo, WQE / 4);
    cvt_split<<<dim3((WPE / 4 + 255) / 256), 256, 0, stream>>>(w_proj, wp_hi, wp_lo, WPE / 4);

    // 1) QKV 1x1 conv: plain bf16 MFMA -> bf16
    gemm_mfma<0, 1><<<dim3(L_S / 128, C3 / 128, N_B), 256, 0, stream>>>(
        wq_hi, nullptr, x_hi, nullptr, qkv_bf, C3, D_F);

    // 2) fused dwconv (+l2norm) + MFMA-layout bf16 pack
    fused_qk<<<dim3(L_S / 256, 16, N_B), 256, 0, stream>>>(qkv_bf, w_dw, Qb, Kb);
    fused_v<<<dim3(L_S / 64, H_N, N_B), 256, 0, stream>>>(qkv_bf, w_dw, Vb);

    // 3) attention -> split bf16 hi/lo directly
    attn2<<<dim3(L_S / 64, H_N, N_B), 256, 0, stream>>>(Qb, Kb, Vb, temp, ao_hi, ao_lo);

    // 4) 3-term split-bf16 proj GEMM -> fp32 out
    gemm_mfma<1, 0><<<dim3(L_S / 128, D_F / 128, N_B), 256, 0, stream>>>(
        wp_hi, wp_lo, ao_hi, ao_lo, out, D_F, D_F);
}